// Round 1
// baseline (446.903 us; speedup 1.0000x reference)
//
#include <hip/hip_runtime.h>
#include <cstdint>
#include <cstddef>

// ---------------------------------------------------------------------------
// NN_each_LN_exp: 33x33 SAME convs on 32x32 maps = dense 1024x1024 linear
// operators -> f16 MFMA GEMMs with fused epilogues. Row layout r = n*4+k:
// the 16x16x32 MFMA acc quad holds all 4 colors of one (n,o) cell.
// R16: (a) pre-expand each/notm/empty masks to f16 in HBM (expand_masks) so
//      every GEMM uses the pure-async ASRC0 path -- removes the byte-unpack
//      VALU that held faA at MfmaUtil 22% / VALUBusy 49%;
//      (b) depth GEMMs build A = NC (*) s in-register from a staged NC tile
//      and a 4KB s-tile (v_pk_mul_f16), deleting P materialization
//      (32MB write + 32MB read + epilogue NC loads, per depth).
// Numerics are bit-identical to R15 (same f16 rounding points).
// Session ledger:
//  - 128x128 tile / acc[4][4] / 16x16x32 frags: measured optimum (R4,R6,R12)
//  - pure-async staging (m97): optimum; sync+prefetch regress (R8,R10)
//  - cooperative launch not graph-capturable (R14)
//  - next lever: 256^2 8-phase schedule (T2/T3/T4/T5) on the uniform body
// ---------------------------------------------------------------------------

typedef _Float16 f16;
typedef __attribute__((ext_vector_type(8))) _Float16 f16x8;
typedef __attribute__((ext_vector_type(4))) float f32x4;

#define NB   4096
#define PIX  1024
#define MR   (NB * 4)

__device__ __forceinline__ void gld_lds16(const void* g, void* l) {
    __builtin_amdgcn_global_load_lds(
        (const __attribute__((address_space(1))) void*)g,
        (__attribute__((address_space(3))) void*)l, 16, 0, 0);
}

// Merged builds: [0,4096) conv mats, [4096,4608) W1 pad, [4608,5632) board
__global__ void build_all(const float* __restrict__ we, const float* __restrict__ wn,
                          const float* __restrict__ wn2, const float* __restrict__ wem,
                          const float* __restrict__ W1, const int* __restrict__ dots,
                          f16* __restrict__ Me, f16* __restrict__ Mn,
                          f16* __restrict__ Mn2, f16* __restrict__ Mem,
                          f16* __restrict__ W1b, unsigned char* __restrict__ board) {
    __shared__ unsigned char tile[64][68];
    int bi = blockIdx.x, t = threadIdx.x;
    if (bi < 4096) {
        int idx = bi * 256 + t;
        int o = idx >> 10, in = idx & 1023;
        int i = o >> 5, j = o & 31, a = in >> 5, b = in & 31;
        int u = a - i + 16, v = b - j + 16;
        bool ok = (u >= 0) && (u < 33) && (v >= 0) && (v < 33);
        int w = u * 33 + v;
        float ve = 0.f, vn = 0.f, vn2 = 0.f, vem = 0.f;
        if (ok) { ve = we[w]; vn = wn[w]; vn2 = wn2[w]; vem = wem[w]; }
        Me[idx]  = (f16)ve;
        Mn[idx]  = (f16)vn;
        Mn2[idx] = (f16)vn2;
        Mem[idx] = (f16)vem;
    } else if (bi < 4608) {
        int idx = (bi - 4096) * 256 + t;
        int j = idx >> 10, i = idx & 1023;
        W1b[idx] = (f16)(j < 100 ? W1[j * 1024 + i] : 0.f);
    } else {
        int bb = bi - 4608;
        int bp = bb & 15, bn = bb >> 4;
        int p0 = bp * 64, n0 = bn * 64;
        int ln = t & 63, lp = t >> 6;
#pragma unroll
        for (int j = 0; j < 16; j++) {
            int p = lp * 16 + j;
            tile[p][ln] = (unsigned char)dots[(size_t)(p0 + p) * 4096 + n0 + ln];
        }
        __syncthreads();
#pragma unroll
        for (int j = 0; j < 16; j++) {
            int n = lp * 16 + j;
            board[(size_t)(n0 + n) * 1024 + p0 + ln] = tile[ln][n];
        }
    }
}

// Expand board -> f16 mask matrices (pure-BW kernel, done ONCE).
// eachF/notmF: [MR][PIX] row r = 4n+k;  emptyF: [NB][PIX].
// [0,8192): each+notm, [8192,10240): empty
__global__ void expand_masks(const unsigned char* __restrict__ board,
                             f16* __restrict__ eachF, f16* __restrict__ notmF,
                             f16* __restrict__ emptyF) {
    int bi = blockIdx.x, t = threadIdx.x;
    if (bi < 8192) {
        int idx = bi * 256 + t;                 // r*128 + w0/8
        int r = idx >> 7, w0 = (idx & 127) << 3;
        int n = r >> 2, k1 = (r & 3) + 1;
        uint64_t bb = *(const uint64_t*)(board + (size_t)n * 1024 + w0);
        f16x8 e, m;
#pragma unroll
        for (int j = 0; j < 8; j++) {
            int bj = (int)((bb >> (8 * j)) & 0xff);
            e[j] = (bj == k1) ? (f16)1.f : (f16)0.f;
            m[j] = (bj != 0 && bj != k1) ? (f16)1.f : (f16)0.f;
        }
        *(f16x8*)(eachF + (size_t)idx * 8) = e;
        *(f16x8*)(notmF + (size_t)idx * 8) = m;
    } else {
        int idx = (bi - 8192) * 256 + t;
        int n = idx >> 7, w0 = (idx & 127) << 3;
        uint64_t bb = *(const uint64_t*)(board + (size_t)n * 1024 + w0);
        f16x8 e;
#pragma unroll
        for (int j = 0; j < 8; j++)
            e[j] = (((bb >> (8 * j)) & 0xff) == 0) ? (f16)1.f : (f16)0.f;
        *(f16x8*)(emptyF + (size_t)idx * 8) = e;
    }
}

// ---------------------------------------------------------------------------
// Generic GEMM body: BM=BN=128, BK=64, 4 waves as 2x2, 16x16x32 MFMA,
// XOR-swizzled chunks, pure-async gld_lds staging for BOTH operands.
// MODE: 0 f16-out ldo
//       2 stage1 fused-mk_sa: L0 = asel + En - NCsel (c>0 else 0);
//         Lsel = L0(f16); Sout = sigmoid(L0)
// ---------------------------------------------------------------------------
template <int MODE>
__device__ __forceinline__ void run_gemm(
    int bjob, int ypx, int nx, char* smem,
    const f16* __restrict__ X, const f16* __restrict__ B,
    const unsigned char* __restrict__ board, const f16* __restrict__ En,
    const f16* __restrict__ NCs, f16* __restrict__ Lsel,
    f16* __restrict__ Sout, f16* __restrict__ outB, int ldo) {
    char* smB = smem;                              // 16 KB
    char* smA = smem + 16384;                      // 16 KB

    const int tid = threadIdx.x;
    const int wv = tid >> 6, ln = tid & 63;
    const int wm = wv >> 1, wn_ = wv & 1;
    const int lr = ln & 15, lq = ln >> 4;

    int xcd = bjob & 7, slot = bjob >> 3;
    int bx = slot % nx;
    int by = xcd * ypx + slot / nx;
    const int rtile = by * 128, otile = bx * 128;

    const f32x4 fz = {0.f, 0.f, 0.f, 0.f};
    f32x4 acc[4][4];
#pragma unroll
    for (int i = 0; i < 4; i++)
#pragma unroll
        for (int j = 0; j < 4; j++) acc[i][j] = fz;

    for (int kb = 0; kb < 1024; kb += 64) {
#pragma unroll
        for (int t = 0; t < 4; t++) {
            int c = (wv * 4 + t) * 64 + ln;
            int row = c >> 3, gcol = (c & 7) ^ (row & 7);
            gld_lds16(B + (size_t)(otile + row) * 1024 + kb + gcol * 8, smB + c * 16);
            gld_lds16(X + (size_t)(rtile + row) * 1024 + kb + gcol * 8, smA + c * 16);
        }
        __syncthreads();

#pragma unroll
        for (int kk = 0; kk < 2; kk++) {
            const int oct = kk * 4 + lq;
            f16x8 af[4], bfr[4];
#pragma unroll
            for (int i = 0; i < 4; i++) {
                int rrow = wm * 64 + i * 16 + lr;
                af[i] = *(const f16x8*)(smA + rrow * 128 + (oct ^ (rrow & 7)) * 16);
            }
#pragma unroll
            for (int j = 0; j < 4; j++) {
                int brow = wn_ * 64 + j * 16 + lr;
                bfr[j] = *(const f16x8*)(smB + brow * 128 + (oct ^ (brow & 7)) * 16);
            }
#pragma unroll
            for (int i = 0; i < 4; i++)
#pragma unroll
                for (int j = 0; j < 4; j++)
                    acc[i][j] = __builtin_amdgcn_mfma_f32_16x16x32_f16(
                        af[i], bfr[j], acc[i][j], 0, 0, 0);
        }
        __syncthreads();
    }

#pragma unroll
    for (int i = 0; i < 4; i++) {
        int rbase = rtile + wm * 64 + i * 16 + lq * 4;
#pragma unroll
        for (int j = 0; j < 4; j++) {
            int o = otile + wn_ * 64 + j * 16 + lr;
            f32x4 a = acc[i][j];
            if (MODE == 0) {
#pragma unroll
                for (int v = 0; v < 4; v++)
                    outB[(size_t)(rbase + v) * ldo + o] = (f16)a[v];
            } else {                               // 2: fused stage1 + mk_sa
                int n = rbase >> 2;
                size_t no = (size_t)n * PIX + o;
                int c = board[no];
                float L = 0.f;
                if (c > 0) {
                    float asel = (c == 1) ? a[0] : (c == 2) ? a[1]
                               : (c == 3) ? a[2] : a[3];
                    float ncsel = (float)NCs[(size_t)(rbase + c - 1) * PIX + o];
                    L = asel + (float)En[no] - ncsel;
                }
                Lsel[no] = (f16)L;
                Sout[no] = (f16)(1.f / (1.f + __expf(-L)));
            }
        }
    }
}

// Phase A-a: [0,1024) NC = notmF @ Mn^T, [1024,1280) En = emptyF @ Mem^T
__global__ void __launch_bounds__(256, 4) gemm_faA(
    const f16* __restrict__ Mn, const f16* __restrict__ Mem,
    const f16* __restrict__ notmF, const f16* __restrict__ emptyF,
    f16* __restrict__ NC, f16* __restrict__ En) {
    __shared__ __attribute__((aligned(16))) char smem[32768];
    int bi = blockIdx.x;
    if (bi < 1024) {
        run_gemm<0>(bi, 16, 8, smem, notmF, Mn, nullptr, nullptr,
                    nullptr, nullptr, nullptr, NC, PIX);
    } else {
        run_gemm<0>(bi - 1024, 4, 8, smem, emptyF, Mem, nullptr, nullptr,
                    nullptr, nullptr, nullptr, En, PIX);
    }
}

// Phase A-b: stage1 GEMM (eachF @ Me^T) with fused mk_sa -> Lsel, S1
__global__ void __launch_bounds__(256, 4) gemm_faB(
    const f16* __restrict__ Me, const f16* __restrict__ eachF,
    const unsigned char* __restrict__ board, const f16* __restrict__ En,
    const f16* __restrict__ NC, f16* __restrict__ Lsel, f16* __restrict__ S1) {
    __shared__ __attribute__((aligned(16))) char smem[32768];
    run_gemm<2>(blockIdx.x, 16, 8, smem, eachF, Me, board, En, NC,
                Lsel, S1, nullptr, 0);
}

// ---------------------------------------------------------------------------
// Depth GEMM: A[r,k] = NC[r,k] * s[r>>2,k] built IN-REGISTER from a staged
// 128x64 NC tile + a 4KB 32x64 s tile (one v_pk_mul_f16 quad per fragment).
// No P materialization. Epilogue: Lnew = Lsel + E + asel (c>0), s = sigmoid;
// writes Lsel + Sout only.
// ---------------------------------------------------------------------------
__global__ void __launch_bounds__(256, 2) gemm_depth(
    const f16* __restrict__ NC, const f16* __restrict__ Mn2,
    const unsigned char* __restrict__ board, const f16* __restrict__ En,
    const f16* __restrict__ Sin, f16* __restrict__ Lsel,
    f16* __restrict__ Sout) {
    __shared__ __attribute__((aligned(16))) char smem[36864];
    char* smB = smem;                              // 16 KB
    char* smA = smem + 16384;                      // 16 KB (NC tile)
    char* smS = smem + 32768;                      // 4 KB  (s tile, 32x64)

    const int tid = threadIdx.x;
    const int wv = tid >> 6, ln = tid & 63;
    const int wm = wv >> 1, wn_ = wv & 1;
    const int lr = ln & 15, lq = ln >> 4;

    int bi = blockIdx.x;
    int xcd = bi & 7, slot = bi >> 3;
    int bx = slot & 7;
    int by = xcd * 16 + (slot >> 3);
    const int rtile = by * 128, otile = bx * 128;
    const int n0 = rtile >> 2;

    const f32x4 fz = {0.f, 0.f, 0.f, 0.f};
    f32x4 acc[4][4];
#pragma unroll
    for (int i = 0; i < 4; i++)
#pragma unroll
        for (int j = 0; j < 4; j++) acc[i][j] = fz;

    for (int kb = 0; kb < 1024; kb += 64) {
#pragma unroll
        for (int t = 0; t < 4; t++) {
            int c = (wv * 4 + t) * 64 + ln;
            int row = c >> 3, gcol = (c & 7) ^ (row & 7);
            gld_lds16(Mn2 + (size_t)(otile + row) * 1024 + kb + gcol * 8, smB + c * 16);
            gld_lds16(NC  + (size_t)(rtile + row) * 1024 + kb + gcol * 8, smA + c * 16);
        }
        {   // s tile: 32 rows x 64 cols, linear layout (reads are 4-way max)
            int row = tid >> 3, col = tid & 7;
            gld_lds16(Sin + (size_t)(n0 + row) * 1024 + kb + col * 8, smS + tid * 16);
        }
        __syncthreads();

#pragma unroll
        for (int kk = 0; kk < 2; kk++) {
            const int oct = kk * 4 + lq;
            f16x8 af[4], bfr[4];
#pragma unroll
            for (int i = 0; i < 4; i++) {
                int rrow = wm * 64 + i * 16 + lr;
                f16x8 nv = *(const f16x8*)(smA + rrow * 128 + (oct ^ (rrow & 7)) * 16);
                f16x8 sv = *(const f16x8*)(smS + (rrow >> 2) * 128 + oct * 16);
                af[i] = nv * sv;                   // v_pk_mul_f16, same rounding as old P store
            }
#pragma unroll
            for (int j = 0; j < 4; j++) {
                int brow = wn_ * 64 + j * 16 + lr;
                bfr[j] = *(const f16x8*)(smB + brow * 128 + (oct ^ (brow & 7)) * 16);
            }
#pragma unroll
            for (int i = 0; i < 4; i++)
#pragma unroll
                for (int j = 0; j < 4; j++)
                    acc[i][j] = __builtin_amdgcn_mfma_f32_16x16x32_f16(
                        af[i], bfr[j], acc[i][j], 0, 0, 0);
        }
        __syncthreads();
    }

#pragma unroll
    for (int i = 0; i < 4; i++) {
        int rbase = rtile + wm * 64 + i * 16 + lq * 4;
#pragma unroll
        for (int j = 0; j < 4; j++) {
            int o = otile + wn_ * 64 + j * 16 + lr;
            f32x4 a = acc[i][j];
            int n = rbase >> 2;
            size_t no = (size_t)n * PIX + o;
            int c = board[no];
            float Lnew = 0.f;
            if (c > 0) {
                float asel = (c == 1) ? a[0] : (c == 2) ? a[1]
                           : (c == 3) ? a[2] : a[3];
                Lnew = (float)Lsel[no] + (float)En[no] + asel;
            }
            Lsel[no] = (f16)Lnew;
            Sout[no] = (f16)(1.f / (1.f + __expf(-Lnew)));
        }
    }
}

// ---------------------------------------------------------------------------
// MLP: X1 = leaky(feat @ W1b^T) per 128-batch block, layers 2+3 fused
// in-block via LDS (two 64-batch passes; xs stride 101; W2 in f16).
// ---------------------------------------------------------------------------
__global__ void __launch_bounds__(256) gemm_mlp_fused(
    const f16* __restrict__ feat, const f16* __restrict__ W1b,
    const float* __restrict__ W2, const float* __restrict__ W3,
    float* __restrict__ out) {
    __shared__ __attribute__((aligned(16))) char smem[47360];
    char* smB = smem;
    char* smA = smem + 16384;

    const int tid = threadIdx.x;
    const int wv = tid >> 6, ln = tid & 63;
    const int wm = wv >> 1, wn_ = wv & 1;
    const int lr = ln & 15, lq = ln >> 4;
    const int rtile = blockIdx.x * 128;            // 32 blocks

    const f32x4 fz = {0.f, 0.f, 0.f, 0.f};
    f32x4 acc[4][4];
#pragma unroll
    for (int i = 0; i < 4; i++)
#pragma unroll
        for (int j = 0; j < 4; j++) acc[i][j] = fz;

    for (int kb = 0; kb < 1024; kb += 64) {
#pragma unroll
        for (int t = 0; t < 4; t++) {
            int c = (wv * 4 + t) * 64 + ln;
            int row = c >> 3, gcol = (c & 7) ^ (row & 7);
            gld_lds16(W1b  + (size_t)row * 1024 + kb + gcol * 8, smB + c * 16);
            gld_lds16(feat + (size_t)(rtile + row) * 1024 + kb + gcol * 8, smA + c * 16);
        }
        __syncthreads();
#pragma unroll
        for (int kk = 0; kk < 2; kk++) {
            const int oct = kk * 4 + lq;
            f16x8 af[4], bfr[4];
#pragma unroll
            for (int i = 0; i < 4; i++) {
                int rrow = wm * 64 + i * 16 + lr;
                af[i] = *(const f16x8*)(smA + rrow * 128 + (oct ^ (rrow & 7)) * 16);
            }
#pragma unroll
            for (int j = 0; j < 4; j++) {
                int brow = wn_ * 64 + j * 16 + lr;
                bfr[j] = *(const f16x8*)(smB + brow * 128 + (oct ^ (brow & 7)) * 16);
            }
#pragma unroll
            for (int i = 0; i < 4; i++)
#pragma unroll
                for (int j = 0; j < 4; j++)
                    acc[i][j] = __builtin_amdgcn_mfma_f32_16x16x32_f16(
                        af[i], bfr[j], acc[i][j], 0, 0, 0);
        }
        __syncthreads();
    }

    // ---- fused layers 2+3 ----
    float* xs  = (float*)smem;                     // [64][101]
    f16*   sW2 = (f16*)(smem + 25856);             // [100][100]
    float* sW3 = (float*)(smem + 45856);           // [100]
    float* red = (float*)(smem + 46272);           // [256]
    for (int idx = tid; idx < 10000; idx += 256) sW2[idx] = (f16)W2[idx];
    if (tid < 100) sW3[tid] = W3[tid];

    for (int half = 0; half < 2; half++) {
        if (wm == half) {
#pragma unroll
            for (int i = 0; i < 4; i++) {
                int rb = i * 16 + lq * 4;
#pragma unroll
                for (int j = 0; j < 4; j++) {
                    int o = wn_ * 64 + j * 16 + lr;
                    if (o < 100) {
                        f32x4 a = acc[i][j];
#pragma unroll
                        for (int v = 0; v < 4; v++) {
                            float x = a[v];
                            xs[(rb + v) * 101 + o] = x > 0.f ? x : 0.2f * x;
                        }
                    }
                }
            }
        }
        __syncthreads();
        int nb = tid >> 2, q = tid & 3;
        const float* xrow = xs + nb * 101;
        float partial = 0.f;
        for (int jj = 0; jj < 25; jj++) {
            int j = q + jj * 4;
            const f16* w2r = sW2 + j * 100;
            float a2 = 0.f;
#pragma unroll
            for (int i = 0; i < 100; i++) a2 += (float)w2r[i] * xrow[i];
            partial += sW3[j] * (a2 > 0.f ? a2 : 0.2f * a2);
        }
        red[tid] = partial;
        __syncthreads();
        if (q == 0)
            out[rtile + half * 64 + nb] = red[tid] + red[tid + 1] + red[tid + 2] + red[tid + 3];
        __syncthreads();
    }
}

extern "C" void kernel_launch(void* const* d_in, const int* in_sizes, int n_in,
                              void* d_out, int out_size, void* d_ws, size_t ws_size,
                              hipStream_t stream) {
    (void)in_sizes; (void)n_in; (void)out_size; (void)ws_size;
    const int*   dots   = (const int*)d_in[0];
    const float* w_each = (const float*)d_in[1];
    const float* w_not  = (const float*)d_in[2];
    const float* w_not2 = (const float*)d_in[3];
    const float* w_emp  = (const float*)d_in[4];
    const float* W1 = (const float*)d_in[5];
    const float* W2 = (const float*)d_in[6];
    const float* W3 = (const float*)d_in[7];
    float* out = (float*)d_out;

    char* ws = (char*)d_ws;
    size_t off = 0;
    auto alloc = [&](size_t bytes) -> char* {
        char* p = ws + off;
        off += (bytes + 255) & ~(size_t)255;
        return p;
    };
    f16* Me    = (f16*)alloc((size_t)PIX * PIX * 2);
    f16* Mn    = (f16*)alloc((size_t)PIX * PIX * 2);
    f16* Mn2   = (f16*)alloc((size_t)PIX * PIX * 2);
    f16* Mem   = (f16*)alloc((size_t)PIX * PIX * 2);
    f16* W1b   = (f16*)alloc((size_t)128 * PIX * 2);
    unsigned char* board = (unsigned char*)alloc((size_t)NB * PIX);
    f16* eachF = (f16*)alloc((size_t)MR * PIX * 2);   // 32 MB
    f16* notmF = (f16*)alloc((size_t)MR * PIX * 2);   // 32 MB
    f16* emptyF= (f16*)alloc((size_t)NB * PIX * 2);   // 8 MB
    f16* NC    = (f16*)alloc((size_t)MR * PIX * 2);   // 32 MB
    f16* En    = (f16*)alloc((size_t)NB * PIX * 2);
    f16* Lsel  = (f16*)alloc((size_t)NB * PIX * 2);
    f16* Sa    = (f16*)alloc((size_t)NB * PIX * 2);
    f16* Sb    = (f16*)alloc((size_t)NB * PIX * 2);

    dim3 blk(256);
    // precompute: conv mats + W1 pad + board transpose
    build_all<<<5632, blk, 0, stream>>>(w_each, w_not, w_not2, w_emp, W1, dots,
                                        Me, Mn, Mn2, Mem, W1b, board);
    // one-shot f16 mask expansion (each/notm/empty)
    expand_masks<<<10240, blk, 0, stream>>>(board, eachF, notmF, emptyF);
    // Phase A-a: NC + En
    gemm_faA<<<1280, blk, 0, stream>>>(Mn, Mem, notmF, emptyF, NC, En);
    // Phase A-b: stage1 with fused mk_sa epilogue -> Lsel, S1 (in Sa)
    gemm_faB<<<1024, blk, 0, stream>>>(Me, eachF, board, En, NC, Lsel, Sa);
    // depth 1..4: A = NC (*) s built in-register; epilogue emits s_{d+1}
    gemm_depth<<<1024, blk, 0, stream>>>(NC, Mn2, board, En, Sa, Lsel, Sb);
    gemm_depth<<<1024, blk, 0, stream>>>(NC, Mn2, board, En, Sb, Lsel, Sa);
    gemm_depth<<<1024, blk, 0, stream>>>(NC, Mn2, board, En, Sa, Lsel, Sb);
    gemm_depth<<<1024, blk, 0, stream>>>(NC, Mn2, board, En, Sb, Lsel, Sa);
    // depth-4 s IS the feature map -> MLP 1+2+3 fused
    gemm_mlp_fused<<<32, blk, 0, stream>>>(Sa, W1b, W2, W3, out);
}